// Round 3
// baseline (2342.248 us; speedup 1.0000x reference)
//
#include <hip/hip_runtime.h>
#include <hip/hip_bf16.h>

typedef __hip_bfloat16 bf16;

// ---- dtype helpers: load-as-float / store-from-float (activations) ----
__device__ inline float ldf(const float* p, size_t i) { return p[i]; }
__device__ inline float ldf(const bf16* p, size_t i) { return (float)p[i]; }
__device__ inline void stf(float* p, size_t i, float v) { p[i] = v; }
__device__ inline void stf(bf16* p, size_t i, float v) { p[i] = (bf16)v; }

// ---------------------------------------------------------------- dtype detect
// Interpret first 512 half-words of x as bf16. If input is truly bf16 (N(0,1)
// data), max|v| ~ 4. If input is fp32, the low half-words have uniform-random
// exponent fields -> max|v| is astronomically large. flag=1 means bf16 input.
__global__ void detect_dtype_kernel(const unsigned short* __restrict__ x, int* __restrict__ flag) {
    __shared__ float s[256];
    float m = 0.0f;
    for (int i = threadIdx.x; i < 512; i += 256) {
        unsigned int u = ((unsigned int)x[i]) << 16;
        float v = __uint_as_float(u);
        if (!isnan(v)) m = fmaxf(m, fabsf(v));
    }
    s[threadIdx.x] = m;
    __syncthreads();
    for (int o = 128; o > 0; o >>= 1) {
        if (threadIdx.x < (unsigned)o) s[threadIdx.x] = fmaxf(s[threadIdx.x], s[threadIdx.x + o]);
        __syncthreads();
    }
    if (threadIdx.x == 0) flag[0] = (s[0] > 1e3f) ? 0 : 1;
}

// convert input tensor (dtype per flag) -> fp32
__global__ void cvt_kernel(const void* __restrict__ in, float* __restrict__ out,
                           int n, const int* __restrict__ flag) {
    int i = blockIdx.x * blockDim.x + threadIdx.x;
    if (i >= n) return;
    if (*flag) out[i] = (float)((const bf16*)in)[i];
    else       out[i] = ((const float*)in)[i];
}

// store fp32 result -> output buffer (dtype per flag, self-consistent with input)
__global__ void out_kernel(const float* __restrict__ in, void* __restrict__ out,
                           int n, const int* __restrict__ flag) {
    int i = blockIdx.x * blockDim.x + threadIdx.x;
    if (i >= n) return;
    if (*flag) ((bf16*)out)[i] = (bf16)in[i];
    else       ((float*)out)[i] = in[i];
}

// ---------------------------------------------------------------- CSR build

__global__ void zero_int_kernel(int* a, int n) {
    int i = blockIdx.x * blockDim.x + threadIdx.x;
    if (i < n) a[i] = 0;
}

__global__ void hist_kernel(const int* __restrict__ col, int* __restrict__ counts, int E) {
    int e = blockIdx.x * blockDim.x + threadIdx.x;
    if (e < E) atomicAdd(&counts[col[e]], 1);
}

// dis[i] = rsqrt(deg[i]) with deg = incoming-count + 1 (self-loop) >= 1 always
__global__ void dis_kernel(const int* __restrict__ counts, float* __restrict__ dis, int n) {
    int i = blockIdx.x * blockDim.x + threadIdx.x;
    if (i < n) dis[i] = rsqrtf((float)(counts[i] + 1));
}

// exclusive scan of counts[0..n) -> offsets[0..n], single block of 1024 threads
__global__ void scan_kernel(const int* __restrict__ counts, int* __restrict__ offsets, int n) {
    __shared__ int sdata[1024];
    int carry = 0;
    if (threadIdx.x == 0) offsets[0] = 0;
    for (int base = 0; base < n; base += 1024) {
        int i = base + (int)threadIdx.x;
        int v = (i < n) ? counts[i] : 0;
        sdata[threadIdx.x] = v;
        __syncthreads();
        for (int off = 1; off < 1024; off <<= 1) {
            int t = (threadIdx.x >= (unsigned)off) ? sdata[threadIdx.x - off] : 0;
            __syncthreads();
            sdata[threadIdx.x] += t;
            __syncthreads();
        }
        int inc = sdata[threadIdx.x] + carry;
        if (i < n) offsets[i + 1] = inc;
        carry += sdata[1023];
        __syncthreads();
    }
}

__global__ void fill_kernel(const int* __restrict__ row, const int* __restrict__ col,
                            const int* __restrict__ offsets, int* __restrict__ cursor,
                            int* __restrict__ csr_src, int E) {
    int e = blockIdx.x * blockDim.x + threadIdx.x;
    if (e < E) {
        int d = col[e];
        int pos = offsets[d] + atomicAdd(&cursor[d], 1);
        csr_src[pos] = row[e];
    }
}

// ---------------------------------------------------------------- aggregation
// out[i,f] = dis[i] * ( dis[i]*h[i,f] + sum_{e in CSR[i]} dis[src_e]*h[src_e,f] )
//            (+ bias[f]) (relu)
template <typename TIn, typename TOut>
__global__ void agg_kernel(const TIn* __restrict__ h, const int* __restrict__ offsets,
                           const int* __restrict__ csr_src, const float* __restrict__ dis,
                           const float* __restrict__ bias, TOut* __restrict__ out,
                           int n, int F, int add_bias, int relu) {
    long long idx = (long long)blockIdx.x * blockDim.x + threadIdx.x;
    long long total = (long long)n * F;
    if (idx >= total) return;
    int i = (int)(idx / F);
    int f = (int)(idx % F);
    float di = dis[i];
    float acc = di * ldf(h, (size_t)i * F + f);
    int e0 = offsets[i], e1 = offsets[i + 1];
    for (int e = e0; e < e1; ++e) {
        int s = csr_src[e];
        acc += dis[s] * ldf(h, (size_t)s * F + f);
    }
    acc *= di;
    if (add_bias) acc += bias[f];
    if (relu) acc = fmaxf(acc, 0.0f);
    stf(out, (size_t)idx, acc);
}

// ---------------------------------------------------------------- GEMMs
// C[M,Nc] = A[M,K] @ W[K,Nc] (fp32 weights) (+bias)(relu). One thread per element.
template <typename TIn, typename TOut>
__global__ void gemm_naive_kernel(const TIn* __restrict__ A, const float* __restrict__ W,
                                  const float* __restrict__ bias, TOut* __restrict__ C,
                                  int M, int Nc, int K, int add_bias, int relu) {
    long long idx = (long long)blockIdx.x * blockDim.x + threadIdx.x;
    long long total = (long long)M * Nc;
    if (idx >= total) return;
    int m = (int)(idx / Nc);
    int nc = (int)(idx % Nc);
    float acc = 0.0f;
    for (int k = 0; k < K; ++k)
        acc += ldf(A, (size_t)m * K + k) * W[(size_t)k * Nc + nc];
    if (add_bias) acc += bias[nc];
    if (relu) acc = fmaxf(acc, 0.0f);
    stf(C, (size_t)idx, acc);
}

// Tiled GEMM: 64x64 tile, block 256 threads, 4x4 per thread, K-tile 16.
// Requires K % 16 == 0 and Nc % 64 == 0. M bounds-checked. fp32 accumulate.
#define TM 64
#define TN 64
#define TK 16
template <typename TIn, typename TOut>
__global__ __launch_bounds__(256) void gemm_tiled_kernel(
        const TIn* __restrict__ A, const float* __restrict__ W,
        const float* __restrict__ bias, TOut* __restrict__ C,
        int M, int Nc, int K, int add_bias, int relu) {
    __shared__ float As[TK][TM + 1];
    __shared__ float Bs[TK][TN + 1];
    int bm = blockIdx.x * TM;
    int bn = blockIdx.y * TN;
    int tid = threadIdx.x;
    int tm = (tid >> 4) << 2;   // (tid/16)*4
    int tn = (tid & 15) << 2;   // (tid%16)*4
    float acc[4][4] = {};
    for (int k0 = 0; k0 < K; k0 += TK) {
        #pragma unroll
        for (int l = 0; l < 4; ++l) {
            int idx = tid + l * 256;           // 0..1023
            int m = idx >> 4;                  // 0..63
            int k = idx & 15;                  // 0..15
            int gm = bm + m;
            As[k][m] = (gm < M) ? ldf(A, (size_t)gm * K + k0 + k) : 0.0f;
        }
        #pragma unroll
        for (int l = 0; l < 4; ++l) {
            int idx = tid + l * 256;
            int k = idx >> 6;                  // 0..15
            int nn = idx & 63;                 // 0..63
            Bs[k][nn] = W[(size_t)(k0 + k) * Nc + bn + nn];
        }
        __syncthreads();
        #pragma unroll
        for (int k = 0; k < TK; ++k) {
            float a[4], b[4];
            #pragma unroll
            for (int i = 0; i < 4; ++i) a[i] = As[k][tm + i];
            #pragma unroll
            for (int j = 0; j < 4; ++j) b[j] = Bs[k][tn + j];
            #pragma unroll
            for (int i = 0; i < 4; ++i)
                #pragma unroll
                for (int j = 0; j < 4; ++j) acc[i][j] += a[i] * b[j];
        }
        __syncthreads();
    }
    #pragma unroll
    for (int i = 0; i < 4; ++i) {
        int gm = bm + tm + i;
        if (gm >= M) continue;
        #pragma unroll
        for (int j = 0; j < 4; ++j) {
            int gn = bn + tn + j;
            float v = acc[i][j];
            if (add_bias) v += bias[gn];
            if (relu) v = fmaxf(v, 0.0f);
            stf(C, (size_t)gm * Nc + gn, v);
        }
    }
}

// ---------------------------------------------------------------- driver

static inline int cdiv(long long a, int b) { return (int)((a + b - 1) / b); }

extern "C" void kernel_launch(void* const* d_in, const int* in_sizes, int n_in,
                              void* d_out, int out_size, void* d_ws, size_t ws_size,
                              hipStream_t stream) {
    const int N = in_sizes[0] / 3;
    const int E = in_sizes[1] / 2;

    const int* edge_index = (const int*)d_in[1];
    const int* row = edge_index;       // sources
    const int* col = edge_index + E;   // destinations

    // ---- workspace layout (~162 MB for N=50000, E=200000) ----
    char* p = (char*)d_ws;
    auto alloc = [&](size_t bytes) {
        void* r = (void*)p;
        p += (bytes + 255) & ~(size_t)255;
        return r;
    };
    void* bufA    = alloc((size_t)N * 2048);             // max(N*1024 bf16, N*512 f32)
    void* bufB    = alloc((size_t)N * 1024);             // max(N*512 bf16, N*256 f32)
    float* dis    = (float*)alloc((size_t)N * sizeof(float));
    int* offsets  = (int*)alloc((size_t)(N + 1) * sizeof(int));
    int* cursor   = (int*)alloc((size_t)N * sizeof(int));
    int* csr_src  = (int*)alloc((size_t)E * sizeof(int));
    int* flag     = (int*)alloc(256);
    float* Wf[8];
    float* bf_[8];
    for (int L = 0; L < 8; ++L) {
        Wf[L]  = (float*)alloc((size_t)in_sizes[2 + 2 * L] * sizeof(float));
        bf_[L] = (float*)alloc((size_t)in_sizes[3 + 2 * L] * sizeof(float));
    }
    size_t needed = (size_t)(p - (char*)d_ws);
    if (ws_size < needed) return;  // clean validation-fail instead of OOB fault

    float* fA = (float*)bufA;  bf16* hA = (bf16*)bufA;
    float* fB = (float*)bufB;  bf16* hB = (bf16*)bufB;

    const int T = 256;

    // ---- dtype detect + convert all inputs to fp32 ----
    detect_dtype_kernel<<<1, 256, 0, stream>>>((const unsigned short*)d_in[0], flag);
    cvt_kernel<<<cdiv((long long)N * 3, T), T, 0, stream>>>(d_in[0], fA, N * 3, flag);
    for (int L = 0; L < 8; ++L) {
        int wsz = in_sizes[2 + 2 * L], bsz = in_sizes[3 + 2 * L];
        cvt_kernel<<<cdiv(wsz, T), T, 0, stream>>>(d_in[2 + 2 * L], Wf[L], wsz, flag);
        cvt_kernel<<<cdiv(bsz, T), T, 0, stream>>>(d_in[3 + 2 * L], bf_[L], bsz, flag);
    }

    // ---- CSR build (by destination) + degree normalization ----
    zero_int_kernel<<<cdiv(N, T), T, 0, stream>>>(cursor, N);
    hist_kernel<<<cdiv(E, T), T, 0, stream>>>(col, cursor, E);
    dis_kernel<<<cdiv(N, T), T, 0, stream>>>(cursor, dis, N);
    scan_kernel<<<1, 1024, 0, stream>>>(cursor, offsets, N);
    zero_int_kernel<<<cdiv(N, T), T, 0, stream>>>(cursor, N);
    fill_kernel<<<cdiv(E, T), T, 0, stream>>>(row, col, offsets, cursor, csr_src, E);

    // Layer schedule (dims 3,64,64,64,128,1024,512,256,2). aggFirst when fin<fout;
    // bias+relu fused into the LAST op of each layer. x is in fA.

    // L0: 3->64, aggFirst. agg f32->f32 (F=3), naive gemm f32->f32 (+b,relu)
    agg_kernel<float, float><<<cdiv((long long)N * 3, T), T, 0, stream>>>(
        fA, offsets, csr_src, dis, nullptr, fB, N, 3, 0, 0);
    gemm_naive_kernel<float, float><<<cdiv((long long)N * 64, T), T, 0, stream>>>(
        fB, Wf[0], bf_[0], fA, N, 64, 3, 1, 1);

    // L1: 64->64, gemmFirst. tiled f32->f32, agg f32->f32 (+b,relu)
    {
        dim3 g(cdiv(N, TM), 64 / TN);
        gemm_tiled_kernel<float, float><<<g, 256, 0, stream>>>(fA, Wf[1], nullptr, fB, N, 64, 64, 0, 0);
        agg_kernel<float, float><<<cdiv((long long)N * 64, T), T, 0, stream>>>(
            fB, offsets, csr_src, dis, bf_[1], fA, N, 64, 1, 1);
    }

    // L2: 64->64, same as L1
    {
        dim3 g(cdiv(N, TM), 64 / TN);
        gemm_tiled_kernel<float, float><<<g, 256, 0, stream>>>(fA, Wf[2], nullptr, fB, N, 64, 64, 0, 0);
        agg_kernel<float, float><<<cdiv((long long)N * 64, T), T, 0, stream>>>(
            fB, offsets, csr_src, dis, bf_[2], fA, N, 64, 1, 1);
    }

    // L3: 64->128, aggFirst. agg f32->f32 (F=64), tiled f32->f32 (+b,relu)
    {
        agg_kernel<float, float><<<cdiv((long long)N * 64, T), T, 0, stream>>>(
            fA, offsets, csr_src, dis, nullptr, fB, N, 64, 0, 0);
        dim3 g(cdiv(N, TM), 128 / TN);
        gemm_tiled_kernel<float, float><<<g, 256, 0, stream>>>(fB, Wf[3], bf_[3], fA, N, 128, 64, 1, 1);
    }

    // L4: 128->1024, aggFirst. agg f32->f32 (F=128), tiled f32->BF16 (+b,relu)
    {
        agg_kernel<float, float><<<cdiv((long long)N * 128, T), T, 0, stream>>>(
            fA, offsets, csr_src, dis, nullptr, fB, N, 128, 0, 0);
        dim3 g(cdiv(N, TM), 1024 / TN);
        gemm_tiled_kernel<float, bf16><<<g, 256, 0, stream>>>(fB, Wf[4], bf_[4], hA, N, 1024, 128, 1, 1);
    }

    // L5: 1024->512, gemmFirst. tiled BF16->BF16, agg bf16->f32 (+b,relu)
    {
        dim3 g(cdiv(N, TM), 512 / TN);
        gemm_tiled_kernel<bf16, bf16><<<g, 256, 0, stream>>>(hA, Wf[5], nullptr, hB, N, 512, 1024, 0, 0);
        agg_kernel<bf16, float><<<cdiv((long long)N * 512, T), T, 0, stream>>>(
            hB, offsets, csr_src, dis, bf_[5], fA, N, 512, 1, 1);
    }

    // L6: 512->256, gemmFirst. tiled f32->f32, agg f32->f32 (+b,relu)
    {
        dim3 g(cdiv(N, TM), 256 / TN);
        gemm_tiled_kernel<float, float><<<g, 256, 0, stream>>>(fA, Wf[6], nullptr, fB, N, 256, 512, 0, 0);
        agg_kernel<float, float><<<cdiv((long long)N * 256, T), T, 0, stream>>>(
            fB, offsets, csr_src, dis, bf_[6], fA, N, 256, 1, 1);
    }

    // L7: 256->2, gemmFirst. naive gemm f32->f32, agg f32->f32 (+b, no relu)
    {
        gemm_naive_kernel<float, float><<<cdiv((long long)N * 2, T), T, 0, stream>>>(
            fA, Wf[7], nullptr, fB, N, 2, 256, 0, 0);
        agg_kernel<float, float><<<cdiv((long long)N * 2, T), T, 0, stream>>>(
            fB, offsets, csr_src, dis, bf_[7], fA, N, 2, 1, 0);
    }

    // fA holds [N,2] fp32 result; store per detected dtype
    out_kernel<<<cdiv((long long)N * 2, T), T, 0, stream>>>(fA, d_out, N * 2, flag);
}

// Round 4
// 965.085 us; speedup vs baseline: 2.4270x; 2.4270x over previous
//
#include <hip/hip_runtime.h>
#include <hip/hip_bf16.h>

typedef __hip_bfloat16 bf16;
typedef __attribute__((ext_vector_type(8))) short short8;
typedef __attribute__((ext_vector_type(4))) float floatx4;

// ---- dtype helpers: load-as-float / store-from-float (activations) ----
__device__ inline float ldf(const float* p, size_t i) { return p[i]; }
__device__ inline float ldf(const bf16* p, size_t i) { return (float)p[i]; }
__device__ inline void stf(float* p, size_t i, float v) { p[i] = v; }
__device__ inline void stf(bf16* p, size_t i, float v) { p[i] = (bf16)v; }

// ---------------------------------------------------------------- dtype detect
// Interpret first 512 half-words of x as bf16. If input is truly bf16 (N(0,1)
// data), max|v| ~ 4. If fp32, low half-words have random exponents -> huge.
__global__ void detect_dtype_kernel(const unsigned short* __restrict__ x, int* __restrict__ flag) {
    __shared__ float s[256];
    float m = 0.0f;
    for (int i = threadIdx.x; i < 512; i += 256) {
        unsigned int u = ((unsigned int)x[i]) << 16;
        float v = __uint_as_float(u);
        if (!isnan(v)) m = fmaxf(m, fabsf(v));
    }
    s[threadIdx.x] = m;
    __syncthreads();
    for (int o = 128; o > 0; o >>= 1) {
        if (threadIdx.x < (unsigned)o) s[threadIdx.x] = fmaxf(s[threadIdx.x], s[threadIdx.x + o]);
        __syncthreads();
    }
    if (threadIdx.x == 0) flag[0] = (s[0] > 1e3f) ? 0 : 1;
}

// convert input tensor (dtype per flag) -> fp32
__global__ void cvt_kernel(const void* __restrict__ in, float* __restrict__ out,
                           int n, const int* __restrict__ flag) {
    int i = blockIdx.x * blockDim.x + threadIdx.x;
    if (i >= n) return;
    if (*flag) out[i] = (float)((const bf16*)in)[i];
    else       out[i] = ((const float*)in)[i];
}

// store fp32 result -> output buffer (dtype per flag)
__global__ void out_kernel(const float* __restrict__ in, void* __restrict__ out,
                           int n, const int* __restrict__ flag) {
    int i = blockIdx.x * blockDim.x + threadIdx.x;
    if (i >= n) return;
    if (*flag) ((bf16*)out)[i] = (bf16)in[i];
    else       ((float*)out)[i] = in[i];
}

// W[K][N] fp32 -> Wt[N][K] bf16  (transpose + cast, once per launch; tiny)
__global__ void wt_kernel(const float* __restrict__ W, bf16* __restrict__ Wt, int K, int N) {
    int idx = blockIdx.x * blockDim.x + threadIdx.x;
    if (idx >= K * N) return;
    int n = idx / K, k = idx % K;
    Wt[idx] = (bf16)W[(size_t)k * N + n];
}

// ---------------------------------------------------------------- CSR build

__global__ void zero_int_kernel(int* a, int n) {
    int i = blockIdx.x * blockDim.x + threadIdx.x;
    if (i < n) a[i] = 0;
}

__global__ void hist_kernel(const int* __restrict__ col, int* __restrict__ counts, int E) {
    int e = blockIdx.x * blockDim.x + threadIdx.x;
    if (e < E) atomicAdd(&counts[col[e]], 1);
}

__global__ void dis_kernel(const int* __restrict__ counts, float* __restrict__ dis, int n) {
    int i = blockIdx.x * blockDim.x + threadIdx.x;
    if (i < n) dis[i] = rsqrtf((float)(counts[i] + 1));
}

__global__ void scan_kernel(const int* __restrict__ counts, int* __restrict__ offsets, int n) {
    __shared__ int sdata[1024];
    int carry = 0;
    if (threadIdx.x == 0) offsets[0] = 0;
    for (int base = 0; base < n; base += 1024) {
        int i = base + (int)threadIdx.x;
        int v = (i < n) ? counts[i] : 0;
        sdata[threadIdx.x] = v;
        __syncthreads();
        for (int off = 1; off < 1024; off <<= 1) {
            int t = (threadIdx.x >= (unsigned)off) ? sdata[threadIdx.x - off] : 0;
            __syncthreads();
            sdata[threadIdx.x] += t;
            __syncthreads();
        }
        int inc = sdata[threadIdx.x] + carry;
        if (i < n) offsets[i + 1] = inc;
        carry += sdata[1023];
        __syncthreads();
    }
}

__global__ void fill_kernel(const int* __restrict__ row, const int* __restrict__ col,
                            const int* __restrict__ offsets, int* __restrict__ cursor,
                            int* __restrict__ csr_src, int E) {
    int e = blockIdx.x * blockDim.x + threadIdx.x;
    if (e < E) {
        int d = col[e];
        int pos = offsets[d] + atomicAdd(&cursor[d], 1);
        csr_src[pos] = row[e];
    }
}

// ---------------------------------------------------------------- aggregation
// out[i,f] = dis[i]*( dis[i]*h[i,f] + sum_e dis[src_e]*h[src_e,f] ) (+b)(relu)
template <typename TIn, typename TOut>
__global__ void agg_kernel(const TIn* __restrict__ h, const int* __restrict__ offsets,
                           const int* __restrict__ csr_src, const float* __restrict__ dis,
                           const float* __restrict__ bias, TOut* __restrict__ out,
                           int n, int F, int add_bias, int relu) {
    long long idx = (long long)blockIdx.x * blockDim.x + threadIdx.x;
    long long total = (long long)n * F;
    if (idx >= total) return;
    int i = (int)(idx / F);
    int f = (int)(idx % F);
    float di = dis[i];
    float acc = di * ldf(h, (size_t)i * F + f);
    int e0 = offsets[i], e1 = offsets[i + 1];
    for (int e = e0; e < e1; ++e) {
        int s = csr_src[e];
        acc += dis[s] * ldf(h, (size_t)s * F + f);
    }
    acc *= di;
    if (add_bias) acc += bias[f];
    if (relu) acc = fmaxf(acc, 0.0f);
    stf(out, (size_t)idx, acc);
}

// ---------------------------------------------------------------- GEMMs
template <typename TIn, typename TOut>
__global__ void gemm_naive_kernel(const TIn* __restrict__ A, const float* __restrict__ W,
                                  const float* __restrict__ bias, TOut* __restrict__ C,
                                  int M, int Nc, int K, int add_bias, int relu) {
    long long idx = (long long)blockIdx.x * blockDim.x + threadIdx.x;
    long long total = (long long)M * Nc;
    if (idx >= total) return;
    int m = (int)(idx / Nc);
    int nc = (int)(idx % Nc);
    float acc = 0.0f;
    for (int k = 0; k < K; ++k)
        acc += ldf(A, (size_t)m * K + k) * W[(size_t)k * Nc + nc];
    if (add_bias) acc += bias[nc];
    if (relu) acc = fmaxf(acc, 0.0f);
    stf(C, (size_t)idx, acc);
}

// fp32 tiled GEMM (small layers L1-L3): 64x64 tile, K%16==0, Nc%64==0.
#define TM 64
#define TN 64
#define TK 16
template <typename TIn, typename TOut>
__global__ __launch_bounds__(256) void gemm_tiled_kernel(
        const TIn* __restrict__ A, const float* __restrict__ W,
        const float* __restrict__ bias, TOut* __restrict__ C,
        int M, int Nc, int K, int add_bias, int relu) {
    __shared__ float As[TK][TM + 1];
    __shared__ float Bs[TK][TN + 1];
    int bm = blockIdx.x * TM;
    int bn = blockIdx.y * TN;
    int tid = threadIdx.x;
    int tm = (tid >> 4) << 2;
    int tn = (tid & 15) << 2;
    float acc[4][4] = {};
    for (int k0 = 0; k0 < K; k0 += TK) {
        #pragma unroll
        for (int l = 0; l < 4; ++l) {
            int idx = tid + l * 256;
            int m = idx >> 4;
            int k = idx & 15;
            int gm = bm + m;
            As[k][m] = (gm < M) ? ldf(A, (size_t)gm * K + k0 + k) : 0.0f;
        }
        #pragma unroll
        for (int l = 0; l < 4; ++l) {
            int idx = tid + l * 256;
            int k = idx >> 6;
            int nn = idx & 63;
            Bs[k][nn] = W[(size_t)(k0 + k) * Nc + bn + nn];
        }
        __syncthreads();
        #pragma unroll
        for (int k = 0; k < TK; ++k) {
            float a[4], b[4];
            #pragma unroll
            for (int i = 0; i < 4; ++i) a[i] = As[k][tm + i];
            #pragma unroll
            for (int j = 0; j < 4; ++j) b[j] = Bs[k][tn + j];
            #pragma unroll
            for (int i = 0; i < 4; ++i)
                #pragma unroll
                for (int j = 0; j < 4; ++j) acc[i][j] += a[i] * b[j];
        }
        __syncthreads();
    }
    #pragma unroll
    for (int i = 0; i < 4; ++i) {
        int gm = bm + tm + i;
        if (gm >= M) continue;
        #pragma unroll
        for (int j = 0; j < 4; ++j) {
            int gn = bn + tn + j;
            float v = acc[i][j];
            if (add_bias) v += bias[gn];
            if (relu) v = fmaxf(v, 0.0f);
            stf(C, (size_t)gm * Nc + gn, v);
        }
    }
}

// ---------------------------------------------------------------- MFMA GEMM
// C[M,Nc] = A[M,K](bf16) @ Bt[Nc,K](bf16)^T, fp32 accum. 128x128 tile, BK=32,
// 4 waves each computing 64x64 via 4x4 grid of mfma_f32_16x16x32_bf16.
// A-frag: lane holds A[m=lane&15][k=(lane>>4)*8+j]  (ds_read_b128 from As[m][k])
// B-frag: lane holds B[n=lane&15][k=(lane>>4)*8+j]  (ds_read_b128 from Bs[n][k])
// C/D:    col=lane&15, row=(lane>>4)*4+reg          (m89/m91-verified layout)
// Requires K%32==0, Nc%128==0. M bounds: staging clamps row, epilogue guards.
template <int DO_BIAS, int DO_RELU, typename TOut>
__global__ __launch_bounds__(256) void gemm_mfma_kernel(
        const bf16* __restrict__ A,   // [M,K]
        const bf16* __restrict__ Bt,  // [Nc,K]
        const float* __restrict__ bias,
        TOut* __restrict__ C,         // [M,Nc]
        int M, int Nc, int K) {
    __shared__ bf16 As[128 * 32];
    __shared__ bf16 Bs[128 * 32];
    const int tid  = threadIdx.x;
    const int wave = tid >> 6;
    const int lane = tid & 63;
    const int bm = blockIdx.x * 128;
    const int bn = blockIdx.y * 128;
    const int wr = (wave >> 1) * 64;   // wave sub-tile row
    const int wc = (wave & 1) * 64;    // wave sub-tile col
    const int fm = lane & 15;
    const int fq = lane >> 4;          // quad index 0..3
    const int fk = fq * 8;

    floatx4 acc[4][4] = {};

    for (int k0 = 0; k0 < K; k0 += 32) {
        __syncthreads();
        // stage 128x32 bf16 tiles: 2 passes x 256 threads x 16B
        #pragma unroll
        for (int p = 0; p < 2; ++p) {
            int e = (p * 256 + tid) * 8;     // bf16 element index 0..4095
            int r = e >> 5;                  // row 0..127
            int c = e & 31;                  // col 0..31
            int gm = bm + r; if (gm > M - 1) gm = M - 1;
            *(uint4*)(&As[e]) = *(const uint4*)(A  + (size_t)gm * K + k0 + c);
            *(uint4*)(&Bs[e]) = *(const uint4*)(Bt + (size_t)(bn + r) * K + k0 + c);
        }
        __syncthreads();
        short8 af[4], bfv[4];
        #pragma unroll
        for (int t = 0; t < 4; ++t) {
            af[t]  = *(const short8*)(&As[(wr + t * 16 + fm) * 32 + fk]);
            bfv[t] = *(const short8*)(&Bs[(wc + t * 16 + fm) * 32 + fk]);
        }
        #pragma unroll
        for (int mt = 0; mt < 4; ++mt)
            #pragma unroll
            for (int nt = 0; nt < 4; ++nt)
                acc[mt][nt] = __builtin_amdgcn_mfma_f32_16x16x32_bf16(
                    af[mt], bfv[nt], acc[mt][nt], 0, 0, 0);
    }

    #pragma unroll
    for (int mt = 0; mt < 4; ++mt) {
        #pragma unroll
        for (int r = 0; r < 4; ++r) {
            int gm = bm + wr + mt * 16 + fq * 4 + r;
            if (gm >= M) continue;
            #pragma unroll
            for (int nt = 0; nt < 4; ++nt) {
                int gn = bn + wc + nt * 16 + fm;
                float v = acc[mt][nt][r];
                if (DO_BIAS) v += bias[gn];
                if (DO_RELU) v = fmaxf(v, 0.0f);
                stf(C, (size_t)gm * Nc + gn, v);
            }
        }
    }
}

// ---------------------------------------------------------------- driver

static inline int cdiv(long long a, int b) { return (int)((a + b - 1) / b); }

extern "C" void kernel_launch(void* const* d_in, const int* in_sizes, int n_in,
                              void* d_out, int out_size, void* d_ws, size_t ws_size,
                              hipStream_t stream) {
    const int N = in_sizes[0] / 3;
    const int E = in_sizes[1] / 2;

    const int* edge_index = (const int*)d_in[1];
    const int* row = edge_index;       // sources
    const int* col = edge_index + E;   // destinations

    // ---- workspace layout (~160 MB for N=50000, E=200000) ----
    char* p = (char*)d_ws;
    auto alloc = [&](size_t bytes) {
        void* r = (void*)p;
        p += (bytes + 255) & ~(size_t)255;
        return r;
    };
    void* bufA    = alloc((size_t)N * 2048);   // max(N*1024 bf16, N*512 f32)
    void* bufB    = alloc((size_t)N * 1024);   // max(N*512 bf16, N*256 f32)
    float* dis    = (float*)alloc((size_t)N * sizeof(float));
    int* offsets  = (int*)alloc((size_t)(N + 1) * sizeof(int));
    int* cursor   = (int*)alloc((size_t)N * sizeof(int));
    int* csr_src  = (int*)alloc((size_t)E * sizeof(int));
    int* flag     = (int*)alloc(256);
    float* Wf[8];
    float* bf_[8];
    for (int L = 0; L < 8; ++L) {
        Wf[L]  = (float*)alloc((size_t)in_sizes[2 + 2 * L] * sizeof(float));
        bf_[L] = (float*)alloc((size_t)in_sizes[3 + 2 * L] * sizeof(float));
    }
    // bf16-transposed weights for MFMA layers (Wt[N][K])
    bf16* Wt4 = (bf16*)alloc((size_t)128 * 1024 * sizeof(bf16));
    bf16* Wt5 = (bf16*)alloc((size_t)1024 * 512 * sizeof(bf16));
    bf16* Wt6 = (bf16*)alloc((size_t)512 * 256 * sizeof(bf16));
    size_t needed = (size_t)(p - (char*)d_ws);
    if (ws_size < needed) return;

    float* fA = (float*)bufA;  bf16* hA = (bf16*)bufA;
    float* fB = (float*)bufB;  bf16* hB = (bf16*)bufB;

    const int T = 256;

    // ---- dtype detect + convert all inputs to fp32 ----
    detect_dtype_kernel<<<1, 256, 0, stream>>>((const unsigned short*)d_in[0], flag);
    cvt_kernel<<<cdiv((long long)N * 3, T), T, 0, stream>>>(d_in[0], fA, N * 3, flag);
    for (int L = 0; L < 8; ++L) {
        int wsz = in_sizes[2 + 2 * L], bsz = in_sizes[3 + 2 * L];
        cvt_kernel<<<cdiv(wsz, T), T, 0, stream>>>(d_in[2 + 2 * L], Wf[L], wsz, flag);
        cvt_kernel<<<cdiv(bsz, T), T, 0, stream>>>(d_in[3 + 2 * L], bf_[L], bsz, flag);
    }
    // bf16 transposed copies of W4/W5/W6
    wt_kernel<<<cdiv(128 * 1024, T), T, 0, stream>>>(Wf[4], Wt4, 128, 1024);
    wt_kernel<<<cdiv(1024 * 512, T), T, 0, stream>>>(Wf[5], Wt5, 1024, 512);
    wt_kernel<<<cdiv(512 * 256, T), T, 0, stream>>>(Wf[6], Wt6, 512, 256);

    // ---- CSR build (by destination) + degree normalization ----
    zero_int_kernel<<<cdiv(N, T), T, 0, stream>>>(cursor, N);
    hist_kernel<<<cdiv(E, T), T, 0, stream>>>(col, cursor, E);
    dis_kernel<<<cdiv(N, T), T, 0, stream>>>(cursor, dis, N);
    scan_kernel<<<1, 1024, 0, stream>>>(cursor, offsets, N);
    zero_int_kernel<<<cdiv(N, T), T, 0, stream>>>(cursor, N);
    fill_kernel<<<cdiv(E, T), T, 0, stream>>>(row, col, offsets, cursor, csr_src, E);

    // Layer schedule (dims 3,64,64,64,128,1024,512,256,2). aggFirst when fin<fout;
    // bias+relu fused into the LAST op of each layer. x is fp32 in fA.

    // L0: 3->64, aggFirst: agg f32 (F=3) -> fB, naive gemm (+b,relu) -> fA
    agg_kernel<float, float><<<cdiv((long long)N * 3, T), T, 0, stream>>>(
        fA, offsets, csr_src, dis, nullptr, fB, N, 3, 0, 0);
    gemm_naive_kernel<float, float><<<cdiv((long long)N * 64, T), T, 0, stream>>>(
        fB, Wf[0], bf_[0], fA, N, 64, 3, 1, 1);

    // L1: 64->64 gemmFirst (fp32 tiled), agg (+b,relu)
    {
        dim3 g(cdiv(N, TM), 64 / TN);
        gemm_tiled_kernel<float, float><<<g, 256, 0, stream>>>(fA, Wf[1], nullptr, fB, N, 64, 64, 0, 0);
        agg_kernel<float, float><<<cdiv((long long)N * 64, T), T, 0, stream>>>(
            fB, offsets, csr_src, dis, bf_[1], fA, N, 64, 1, 1);
    }

    // L2: 64->64 same
    {
        dim3 g(cdiv(N, TM), 64 / TN);
        gemm_tiled_kernel<float, float><<<g, 256, 0, stream>>>(fA, Wf[2], nullptr, fB, N, 64, 64, 0, 0);
        agg_kernel<float, float><<<cdiv((long long)N * 64, T), T, 0, stream>>>(
            fB, offsets, csr_src, dis, bf_[2], fA, N, 64, 1, 1);
    }

    // L3: 64->128 aggFirst: agg f32 (F=64) -> fB, tiled (+b,relu) -> fA [N,128] f32
    {
        agg_kernel<float, float><<<cdiv((long long)N * 64, T), T, 0, stream>>>(
            fA, offsets, csr_src, dis, nullptr, fB, N, 64, 0, 0);
        dim3 g(cdiv(N, TM), 128 / TN);
        gemm_tiled_kernel<float, float><<<g, 256, 0, stream>>>(fB, Wf[3], bf_[3], fA, N, 128, 64, 1, 1);
    }

    // L4: 128->1024 aggFirst: agg f32->BF16 (F=128) -> hB, MFMA (+b,relu) -> hA [N,1024] bf16
    {
        agg_kernel<float, bf16><<<cdiv((long long)N * 128, T), T, 0, stream>>>(
            fA, offsets, csr_src, dis, nullptr, hB, N, 128, 0, 0);
        dim3 g(cdiv(N, 128), 1024 / 128);
        gemm_mfma_kernel<1, 1, bf16><<<g, 256, 0, stream>>>(hB, Wt4, bf_[4], hA, N, 1024, 128);
    }

    // L5: 1024->512 gemmFirst: MFMA -> hB [N,512] bf16, agg bf16->bf16 (+b,relu) -> hA
    {
        dim3 g(cdiv(N, 128), 512 / 128);
        gemm_mfma_kernel<0, 0, bf16><<<g, 256, 0, stream>>>(hA, Wt5, nullptr, hB, N, 512, 1024);
        agg_kernel<bf16, bf16><<<cdiv((long long)N * 512, T), T, 0, stream>>>(
            hB, offsets, csr_src, dis, bf_[5], hA, N, 512, 1, 1);
    }

    // L6: 512->256 gemmFirst: MFMA -> fB [N,256] f32, agg f32 (+b,relu) -> fA
    {
        dim3 g(cdiv(N, 128), 256 / 128);
        gemm_mfma_kernel<0, 0, float><<<g, 256, 0, stream>>>(hA, Wt6, nullptr, fB, N, 256, 512);
        agg_kernel<float, float><<<cdiv((long long)N * 256, T), T, 0, stream>>>(
            fB, offsets, csr_src, dis, bf_[6], fA, N, 256, 1, 1);
    }

    // L7: 256->2 gemmFirst: naive f32 -> fB [N,2], agg (+b, no relu) -> fA
    {
        gemm_naive_kernel<float, float><<<cdiv((long long)N * 2, T), T, 0, stream>>>(
            fA, Wf[7], nullptr, fB, N, 2, 256, 0, 0);
        agg_kernel<float, float><<<cdiv((long long)N * 2, T), T, 0, stream>>>(
            fB, offsets, csr_src, dis, bf_[7], fA, N, 2, 1, 0);
    }

    out_kernel<<<cdiv((long long)N * 2, T), T, 0, stream>>>(fA, d_out, N * 2, flag);
}

// Round 5
// 707.296 us; speedup vs baseline: 3.3116x; 1.3645x over previous
//
#include <hip/hip_runtime.h>
#include <hip/hip_bf16.h>

typedef __hip_bfloat16 bf16;
typedef __attribute__((ext_vector_type(8))) short short8;
typedef __attribute__((ext_vector_type(4))) float floatx4;

// ---- dtype helpers: load-as-float / store-from-float (activations) ----
__device__ inline float ldf(const float* p, size_t i) { return p[i]; }
__device__ inline float ldf(const bf16* p, size_t i) { return (float)p[i]; }
__device__ inline void stf(float* p, size_t i, float v) { p[i] = v; }
__device__ inline void stf(bf16* p, size_t i, float v) { p[i] = (bf16)v; }

// ---- 16B vector load of VEC elements -> fp32 lanes ----
__device__ inline void loadvec(const float* __restrict__ p, float* d) {   // VEC=4
    float4 v = *(const float4*)p;
    d[0] = v.x; d[1] = v.y; d[2] = v.z; d[3] = v.w;
}
__device__ inline void loadvec(const bf16* __restrict__ p, float* d) {    // VEC=8
    uint4 u = *(const uint4*)p;
    const unsigned* w = (const unsigned*)&u;
    #pragma unroll
    for (int j = 0; j < 4; ++j) {
        d[2 * j]     = __uint_as_float(w[j] << 16);
        d[2 * j + 1] = __uint_as_float(w[j] & 0xffff0000u);
    }
}
template <int VEC, typename TOut>
__device__ inline void storevec(TOut* __restrict__ p, const float* d) {
    if constexpr (sizeof(TOut) == 4) {
        #pragma unroll
        for (int j = 0; j < VEC; j += 4) {
            float4 v = {d[j], d[j + 1], d[j + 2], d[j + 3]};
            *(float4*)(p + j) = v;
        }
    } else {
        unsigned w[VEC / 2];
        #pragma unroll
        for (int j = 0; j < VEC / 2; ++j) {
            bf16 lo = (bf16)d[2 * j], hi = (bf16)d[2 * j + 1];
            w[j] = ((unsigned)*(unsigned short*)&hi << 16) | (unsigned)*(unsigned short*)&lo;
        }
        if constexpr (VEC == 8) *(uint4*)p = *(uint4*)&w[0];
        else                    *(uint2*)p = *(uint2*)&w[0];
    }
}

// ---------------------------------------------------------------- dtype detect
__global__ void detect_dtype_kernel(const unsigned short* __restrict__ x, int* __restrict__ flag) {
    __shared__ float s[256];
    float m = 0.0f;
    for (int i = threadIdx.x; i < 512; i += 256) {
        unsigned int u = ((unsigned int)x[i]) << 16;
        float v = __uint_as_float(u);
        if (!isnan(v)) m = fmaxf(m, fabsf(v));
    }
    s[threadIdx.x] = m;
    __syncthreads();
    for (int o = 128; o > 0; o >>= 1) {
        if (threadIdx.x < (unsigned)o) s[threadIdx.x] = fmaxf(s[threadIdx.x], s[threadIdx.x + o]);
        __syncthreads();
    }
    if (threadIdx.x == 0) flag[0] = (s[0] > 1e3f) ? 0 : 1;
}

__global__ void cvt_kernel(const void* __restrict__ in, float* __restrict__ out,
                           int n, const int* __restrict__ flag) {
    int i = blockIdx.x * blockDim.x + threadIdx.x;
    if (i >= n) return;
    if (*flag) out[i] = (float)((const bf16*)in)[i];
    else       out[i] = ((const float*)in)[i];
}

__global__ void out_kernel(const float* __restrict__ in, void* __restrict__ out,
                           int n, const int* __restrict__ flag) {
    int i = blockIdx.x * blockDim.x + threadIdx.x;
    if (i >= n) return;
    if (*flag) ((bf16*)out)[i] = (bf16)in[i];
    else       ((float*)out)[i] = in[i];
}

// W[K][N] fp32 -> Wt[N][K] bf16
__global__ void wt_kernel(const float* __restrict__ W, bf16* __restrict__ Wt, int K, int N) {
    int idx = blockIdx.x * blockDim.x + threadIdx.x;
    if (idx >= K * N) return;
    int n = idx / K, k = idx % K;
    Wt[idx] = (bf16)W[(size_t)k * N + n];
}

// ---------------------------------------------------------------- CSR build

__global__ void zero_int_kernel(int* a, int n) {
    int i = blockIdx.x * blockDim.x + threadIdx.x;
    if (i < n) a[i] = 0;
}

__global__ void hist_kernel(const int* __restrict__ col, int* __restrict__ counts, int E) {
    int e = blockIdx.x * blockDim.x + threadIdx.x;
    if (e < E) atomicAdd(&counts[col[e]], 1);
}

__global__ void dis_kernel(const int* __restrict__ counts, float* __restrict__ dis, int n) {
    int i = blockIdx.x * blockDim.x + threadIdx.x;
    if (i < n) dis[i] = rsqrtf((float)(counts[i] + 1));
}

__global__ void scan_kernel(const int* __restrict__ counts, int* __restrict__ offsets, int n) {
    __shared__ int sdata[1024];
    int carry = 0;
    if (threadIdx.x == 0) offsets[0] = 0;
    for (int base = 0; base < n; base += 1024) {
        int i = base + (int)threadIdx.x;
        int v = (i < n) ? counts[i] : 0;
        sdata[threadIdx.x] = v;
        __syncthreads();
        for (int off = 1; off < 1024; off <<= 1) {
            int t = (threadIdx.x >= (unsigned)off) ? sdata[threadIdx.x - off] : 0;
            __syncthreads();
            sdata[threadIdx.x] += t;
            __syncthreads();
        }
        int inc = sdata[threadIdx.x] + carry;
        if (i < n) offsets[i + 1] = inc;
        carry += sdata[1023];
        __syncthreads();
    }
}

__global__ void fill_kernel(const int* __restrict__ row, const int* __restrict__ col,
                            const int* __restrict__ offsets, int* __restrict__ cursor,
                            int* __restrict__ csr_src, int E) {
    int e = blockIdx.x * blockDim.x + threadIdx.x;
    if (e < E) {
        int d = col[e];
        int pos = offsets[d] + atomicAdd(&cursor[d], 1);
        csr_src[pos] = row[e];
    }
}

// ---------------------------------------------------------------- aggregation
// scalar version (tiny F only: F=3, F=2)
template <typename TIn, typename TOut>
__global__ void agg_kernel(const TIn* __restrict__ h, const int* __restrict__ offsets,
                           const int* __restrict__ csr_src, const float* __restrict__ dis,
                           const float* __restrict__ bias, TOut* __restrict__ out,
                           int n, int F, int add_bias, int relu) {
    long long idx = (long long)blockIdx.x * blockDim.x + threadIdx.x;
    long long total = (long long)n * F;
    if (idx >= total) return;
    int i = (int)(idx / F);
    int f = (int)(idx % F);
    float di = dis[i];
    float acc = di * ldf(h, (size_t)i * F + f);
    int e0 = offsets[i], e1 = offsets[i + 1];
    for (int e = e0; e < e1; ++e) {
        int s = csr_src[e];
        acc += dis[s] * ldf(h, (size_t)s * F + f);
    }
    acc *= di;
    if (add_bias) acc += bias[f];
    if (relu) acc = fmaxf(acc, 0.0f);
    stf(out, (size_t)idx, acc);
}

// vectorized version: thread owns VEC consecutive features (16B loads).
// out[i,f] = dis[i]*( dis[i]*h[i,f] + sum_e dis[src_e]*h[src_e,f] ) (+b)(relu)
template <int F, int DO_BIAS, int DO_RELU, typename TIn, typename TOut>
__global__ __launch_bounds__(256) void agg_vec_kernel(
        const TIn* __restrict__ h, const int* __restrict__ offsets,
        const int* __restrict__ csr_src, const float* __restrict__ dis,
        const float* __restrict__ bias, TOut* __restrict__ out, int n) {
    constexpr int VEC = 16 / sizeof(TIn);   // 8 for bf16, 4 for f32
    constexpr int CPL = F / VEC;            // chunks per node row
    int t = blockIdx.x * 256 + threadIdx.x;
    if (t >= n * CPL) return;
    int i = t / CPL;
    int c = t % CPL;
    int fbase = c * VEC;
    float di = dis[i];
    float acc[VEC];
    loadvec(h + (size_t)i * F + fbase, acc);
    #pragma unroll
    for (int v = 0; v < VEC; ++v) acc[v] *= di;
    int e0 = offsets[i], e1 = offsets[i + 1];
    for (int e = e0; e < e1; ++e) {
        int s = csr_src[e];
        float dsv = dis[s];
        float tmp[VEC];
        loadvec(h + (size_t)s * F + fbase, tmp);
        #pragma unroll
        for (int v = 0; v < VEC; ++v) acc[v] += dsv * tmp[v];
    }
    #pragma unroll
    for (int v = 0; v < VEC; ++v) {
        acc[v] *= di;
        if (DO_BIAS) acc[v] += bias[fbase + v];
        if (DO_RELU) acc[v] = fmaxf(acc[v], 0.0f);
    }
    storevec<VEC>(out + (size_t)i * F + fbase, acc);
}

// ---------------------------------------------------------------- GEMMs
template <typename TIn, typename TOut>
__global__ void gemm_naive_kernel(const TIn* __restrict__ A, const float* __restrict__ W,
                                  const float* __restrict__ bias, TOut* __restrict__ C,
                                  int M, int Nc, int K, int add_bias, int relu) {
    long long idx = (long long)blockIdx.x * blockDim.x + threadIdx.x;
    long long total = (long long)M * Nc;
    if (idx >= total) return;
    int m = (int)(idx / Nc);
    int nc = (int)(idx % Nc);
    float acc = 0.0f;
    for (int k = 0; k < K; ++k)
        acc += ldf(A, (size_t)m * K + k) * W[(size_t)k * Nc + nc];
    if (add_bias) acc += bias[nc];
    if (relu) acc = fmaxf(acc, 0.0f);
    stf(C, (size_t)idx, acc);
}

// fp32 tiled GEMM (small layers L1-L3): 64x64 tile, K%16==0, Nc%64==0.
#define TM 64
#define TN 64
#define TK 16
template <typename TIn, typename TOut>
__global__ __launch_bounds__(256) void gemm_tiled_kernel(
        const TIn* __restrict__ A, const float* __restrict__ W,
        const float* __restrict__ bias, TOut* __restrict__ C,
        int M, int Nc, int K, int add_bias, int relu) {
    __shared__ float As[TK][TM + 1];
    __shared__ float Bs[TK][TN + 1];
    int bm = blockIdx.x * TM;
    int bn = blockIdx.y * TN;
    int tid = threadIdx.x;
    int tm = (tid >> 4) << 2;
    int tn = (tid & 15) << 2;
    float acc[4][4] = {};
    for (int k0 = 0; k0 < K; k0 += TK) {
        #pragma unroll
        for (int l = 0; l < 4; ++l) {
            int idx = tid + l * 256;
            int m = idx >> 4;
            int k = idx & 15;
            int gm = bm + m;
            As[k][m] = (gm < M) ? ldf(A, (size_t)gm * K + k0 + k) : 0.0f;
        }
        #pragma unroll
        for (int l = 0; l < 4; ++l) {
            int idx = tid + l * 256;
            int k = idx >> 6;
            int nn = idx & 63;
            Bs[k][nn] = W[(size_t)(k0 + k) * Nc + bn + nn];
        }
        __syncthreads();
        #pragma unroll
        for (int k = 0; k < TK; ++k) {
            float a[4], b[4];
            #pragma unroll
            for (int i = 0; i < 4; ++i) a[i] = As[k][tm + i];
            #pragma unroll
            for (int j = 0; j < 4; ++j) b[j] = Bs[k][tn + j];
            #pragma unroll
            for (int i = 0; i < 4; ++i)
                #pragma unroll
                for (int j = 0; j < 4; ++j) acc[i][j] += a[i] * b[j];
        }
        __syncthreads();
    }
    #pragma unroll
    for (int i = 0; i < 4; ++i) {
        int gm = bm + tm + i;
        if (gm >= M) continue;
        #pragma unroll
        for (int j = 0; j < 4; ++j) {
            int gn = bn + tn + j;
            float v = acc[i][j];
            if (add_bias) v += bias[gn];
            if (relu) v = fmaxf(v, 0.0f);
            stf(C, (size_t)gm * Nc + gn, v);
        }
    }
}

// ---------------------------------------------------------------- MFMA GEMM
// C[M,Nc] = A[M,K](bf16) @ Bt[Nc,K](bf16)^T, fp32 accum. 128x128 tile, BK=32.
template <int DO_BIAS, int DO_RELU, typename TOut>
__global__ __launch_bounds__(256) void gemm_mfma_kernel(
        const bf16* __restrict__ A,   // [M,K]
        const bf16* __restrict__ Bt,  // [Nc,K]
        const float* __restrict__ bias,
        TOut* __restrict__ C,         // [M,Nc]
        int M, int Nc, int K) {
    __shared__ bf16 As[128 * 32];
    __shared__ bf16 Bs[128 * 32];
    const int tid  = threadIdx.x;
    const int wave = tid >> 6;
    const int lane = tid & 63;
    const int bm = blockIdx.x * 128;
    const int bn = blockIdx.y * 128;
    const int wr = (wave >> 1) * 64;
    const int wc = (wave & 1) * 64;
    const int fm = lane & 15;
    const int fq = lane >> 4;
    const int fk = fq * 8;

    floatx4 acc[4][4] = {};

    for (int k0 = 0; k0 < K; k0 += 32) {
        __syncthreads();
        #pragma unroll
        for (int p = 0; p < 2; ++p) {
            int e = (p * 256 + tid) * 8;
            int r = e >> 5;
            int c = e & 31;
            int gm = bm + r; if (gm > M - 1) gm = M - 1;
            *(uint4*)(&As[e]) = *(const uint4*)(A  + (size_t)gm * K + k0 + c);
            *(uint4*)(&Bs[e]) = *(const uint4*)(Bt + (size_t)(bn + r) * K + k0 + c);
        }
        __syncthreads();
        short8 af[4], bfv[4];
        #pragma unroll
        for (int t = 0; t < 4; ++t) {
            af[t]  = *(const short8*)(&As[(wr + t * 16 + fm) * 32 + fk]);
            bfv[t] = *(const short8*)(&Bs[(wc + t * 16 + fm) * 32 + fk]);
        }
        #pragma unroll
        for (int mt = 0; mt < 4; ++mt)
            #pragma unroll
            for (int nt = 0; nt < 4; ++nt)
                acc[mt][nt] = __builtin_amdgcn_mfma_f32_16x16x32_bf16(
                    af[mt], bfv[nt], acc[mt][nt], 0, 0, 0);
    }

    #pragma unroll
    for (int mt = 0; mt < 4; ++mt) {
        #pragma unroll
        for (int r = 0; r < 4; ++r) {
            int gm = bm + wr + mt * 16 + fq * 4 + r;
            if (gm >= M) continue;
            #pragma unroll
            for (int nt = 0; nt < 4; ++nt) {
                int gn = bn + wc + nt * 16 + fm;
                float v = acc[mt][nt][r];
                if (DO_BIAS) v += bias[gn];
                if (DO_RELU) v = fmaxf(v, 0.0f);
                stf(C, (size_t)gm * Nc + gn, v);
            }
        }
    }
}

// ---------------------------------------------------------------- driver

static inline int cdiv(long long a, int b) { return (int)((a + b - 1) / b); }

extern "C" void kernel_launch(void* const* d_in, const int* in_sizes, int n_in,
                              void* d_out, int out_size, void* d_ws, size_t ws_size,
                              hipStream_t stream) {
    const int N = in_sizes[0] / 3;
    const int E = in_sizes[1] / 2;

    const int* edge_index = (const int*)d_in[1];
    const int* row = edge_index;       // sources
    const int* col = edge_index + E;   // destinations

    char* p = (char*)d_ws;
    auto alloc = [&](size_t bytes) {
        void* r = (void*)p;
        p += (bytes + 255) & ~(size_t)255;
        return r;
    };
    void* bufA    = alloc((size_t)N * 2048);   // max(N*1024 bf16, N*512 f32)
    void* bufB    = alloc((size_t)N * 1024);   // max(N*512 bf16, N*256 f32)
    float* dis    = (float*)alloc((size_t)N * sizeof(float));
    int* offsets  = (int*)alloc((size_t)(N + 1) * sizeof(int));
    int* cursor   = (int*)alloc((size_t)N * sizeof(int));
    int* csr_src  = (int*)alloc((size_t)E * sizeof(int));
    int* flag     = (int*)alloc(256);
    float* Wf[8];
    float* bf_[8];
    for (int L = 0; L < 8; ++L) {
        Wf[L]  = (float*)alloc((size_t)in_sizes[2 + 2 * L] * sizeof(float));
        bf_[L] = (float*)alloc((size_t)in_sizes[3 + 2 * L] * sizeof(float));
    }
    bf16* Wt4 = (bf16*)alloc((size_t)128 * 1024 * sizeof(bf16));
    bf16* Wt5 = (bf16*)alloc((size_t)1024 * 512 * sizeof(bf16));
    bf16* Wt6 = (bf16*)alloc((size_t)512 * 256 * sizeof(bf16));
    size_t needed = (size_t)(p - (char*)d_ws);
    if (ws_size < needed) return;

    float* fA = (float*)bufA;  bf16* hA = (bf16*)bufA;
    float* fB = (float*)bufB;  bf16* hB = (bf16*)bufB;

    const int T = 256;

    // ---- dtype detect + convert inputs to fp32 ----
    detect_dtype_kernel<<<1, 256, 0, stream>>>((const unsigned short*)d_in[0], flag);
    cvt_kernel<<<cdiv((long long)N * 3, T), T, 0, stream>>>(d_in[0], fA, N * 3, flag);
    for (int L = 0; L < 8; ++L) {
        int wsz = in_sizes[2 + 2 * L], bsz = in_sizes[3 + 2 * L];
        cvt_kernel<<<cdiv(wsz, T), T, 0, stream>>>(d_in[2 + 2 * L], Wf[L], wsz, flag);
        cvt_kernel<<<cdiv(bsz, T), T, 0, stream>>>(d_in[3 + 2 * L], bf_[L], bsz, flag);
    }
    wt_kernel<<<cdiv(128 * 1024, T), T, 0, stream>>>(Wf[4], Wt4, 128, 1024);
    wt_kernel<<<cdiv(1024 * 512, T), T, 0, stream>>>(Wf[5], Wt5, 1024, 512);
    wt_kernel<<<cdiv(512 * 256, T), T, 0, stream>>>(Wf[6], Wt6, 512, 256);

    // ---- CSR build ----
    zero_int_kernel<<<cdiv(N, T), T, 0, stream>>>(cursor, N);
    hist_kernel<<<cdiv(E, T), T, 0, stream>>>(col, cursor, E);
    dis_kernel<<<cdiv(N, T), T, 0, stream>>>(cursor, dis, N);
    scan_kernel<<<1, 1024, 0, stream>>>(cursor, offsets, N);
    zero_int_kernel<<<cdiv(N, T), T, 0, stream>>>(cursor, N);
    fill_kernel<<<cdiv(E, T), T, 0, stream>>>(row, col, offsets, cursor, csr_src, E);

    // Layer schedule (dims 3,64,64,64,128,1024,512,256,2). aggFirst when fin<fout.

    // L0: 3->64 aggFirst: scalar agg (F=3) -> fB, naive gemm (+b,relu) -> fA
    agg_kernel<float, float><<<cdiv((long long)N * 3, T), T, 0, stream>>>(
        fA, offsets, csr_src, dis, nullptr, fB, N, 3, 0, 0);
    gemm_naive_kernel<float, float><<<cdiv((long long)N * 64, T), T, 0, stream>>>(
        fB, Wf[0], bf_[0], fA, N, 64, 3, 1, 1);

    // L1: 64->64 gemmFirst: tiled f32 -> fB, agg_vec (+b,relu) -> fA
    {
        dim3 g(cdiv(N, TM), 64 / TN);
        gemm_tiled_kernel<float, float><<<g, 256, 0, stream>>>(fA, Wf[1], nullptr, fB, N, 64, 64, 0, 0);
        agg_vec_kernel<64, 1, 1, float, float><<<cdiv((long long)N * 16, T), T, 0, stream>>>(
            fB, offsets, csr_src, dis, bf_[1], fA, N);
    }

    // L2: 64->64 same
    {
        dim3 g(cdiv(N, TM), 64 / TN);
        gemm_tiled_kernel<float, float><<<g, 256, 0, stream>>>(fA, Wf[2], nullptr, fB, N, 64, 64, 0, 0);
        agg_vec_kernel<64, 1, 1, float, float><<<cdiv((long long)N * 16, T), T, 0, stream>>>(
            fB, offsets, csr_src, dis, bf_[2], fA, N);
    }

    // L3: 64->128 aggFirst: agg_vec f32 (F=64) -> fB, tiled (+b,relu) -> hA [N,128] bf16
    {
        agg_vec_kernel<64, 0, 0, float, float><<<cdiv((long long)N * 16, T), T, 0, stream>>>(
            fA, offsets, csr_src, dis, nullptr, fB, N);
        dim3 g(cdiv(N, TM), 128 / TN);
        gemm_tiled_kernel<float, bf16><<<g, 256, 0, stream>>>(fB, Wf[3], bf_[3], hA, N, 128, 64, 1, 1);
    }

    // L4: 128->1024 aggFirst: agg_vec bf16 (F=128) -> hB, MFMA (+b,relu) -> hA [N,1024] bf16
    {
        agg_vec_kernel<128, 0, 0, bf16, bf16><<<cdiv((long long)N * 16, T), T, 0, stream>>>(
            hA, offsets, csr_src, dis, nullptr, hB, N);
        dim3 g(cdiv(N, 128), 1024 / 128);
        gemm_mfma_kernel<1, 1, bf16><<<g, 256, 0, stream>>>(hB, Wt4, bf_[4], hA, N, 1024, 128);
    }

    // L5: 1024->512 gemmFirst: MFMA -> hB [N,512] bf16, agg_vec (+b,relu) -> hA bf16
    {
        dim3 g(cdiv(N, 128), 512 / 128);
        gemm_mfma_kernel<0, 0, bf16><<<g, 256, 0, stream>>>(hA, Wt5, nullptr, hB, N, 512, 1024);
        agg_vec_kernel<512, 1, 1, bf16, bf16><<<cdiv((long long)N * 64, T), T, 0, stream>>>(
            hB, offsets, csr_src, dis, bf_[5], hA, N);
    }

    // L6: 512->256 gemmFirst: MFMA -> hB [N,256] bf16, agg_vec (+b,relu) -> fA f32
    {
        dim3 g(cdiv(N, 128), 256 / 128);
        gemm_mfma_kernel<0, 0, bf16><<<g, 256, 0, stream>>>(hA, Wt6, nullptr, hB, N, 256, 512);
        agg_vec_kernel<256, 1, 1, bf16, float><<<cdiv((long long)N * 32, T), T, 0, stream>>>(
            hB, offsets, csr_src, dis, bf_[6], fA, N);
    }

    // L7: 256->2 gemmFirst: naive f32 -> fB [N,2], scalar agg (+b, no relu) -> fA
    {
        gemm_naive_kernel<float, float><<<cdiv((long long)N * 2, T), T, 0, stream>>>(
            fA, Wf[7], nullptr, fB, N, 2, 256, 0, 0);
        agg_kernel<float, float><<<cdiv((long long)N * 2, T), T, 0, stream>>>(
            fB, offsets, csr_src, dis, bf_[7], fA, N, 2, 1, 0);
    }

    out_kernel<<<cdiv((long long)N * 2, T), T, 0, stream>>>(fA, d_out, N * 2, flag);
}

// Round 6
// 682.384 us; speedup vs baseline: 3.4324x; 1.0365x over previous
//
#include <hip/hip_runtime.h>
#include <hip/hip_bf16.h>

typedef __hip_bfloat16 bf16;
typedef __attribute__((ext_vector_type(8))) short short8;
typedef __attribute__((ext_vector_type(4))) float floatx4;

// ---- dtype helpers ----
__device__ inline float ldf(const float* p, size_t i) { return p[i]; }
__device__ inline float ldf(const bf16* p, size_t i) { return (float)p[i]; }
__device__ inline void stf(float* p, size_t i, float v) { p[i] = v; }
__device__ inline void stf(bf16* p, size_t i, float v) { p[i] = (bf16)v; }

// ---- async global->LDS 16B copy (m97 ladder step) ----
__device__ inline void async16(const bf16* g, bf16* l) {
    __builtin_amdgcn_global_load_lds(
        (const __attribute__((address_space(1))) void*)g,
        (__attribute__((address_space(3))) void*)l, 16, 0, 0);
}

// ---- 16B vector load of VEC elements -> fp32 lanes ----
__device__ inline void loadvec(const float* __restrict__ p, float* d) {   // VEC=4
    float4 v = *(const float4*)p;
    d[0] = v.x; d[1] = v.y; d[2] = v.z; d[3] = v.w;
}
__device__ inline void loadvec(const bf16* __restrict__ p, float* d) {    // VEC=8
    uint4 u = *(const uint4*)p;
    const unsigned* w = (const unsigned*)&u;
    #pragma unroll
    for (int j = 0; j < 4; ++j) {
        d[2 * j]     = __uint_as_float(w[j] << 16);
        d[2 * j + 1] = __uint_as_float(w[j] & 0xffff0000u);
    }
}
template <int VEC, typename TOut>
__device__ inline void storevec(TOut* __restrict__ p, const float* d) {
    if constexpr (sizeof(TOut) == 4) {
        #pragma unroll
        for (int j = 0; j < VEC; j += 4) {
            float4 v = {d[j], d[j + 1], d[j + 2], d[j + 3]};
            *(float4*)(p + j) = v;
        }
    } else {
        unsigned w[VEC / 2];
        #pragma unroll
        for (int j = 0; j < VEC / 2; ++j) {
            bf16 lo = (bf16)d[2 * j], hi = (bf16)d[2 * j + 1];
            w[j] = ((unsigned)*(unsigned short*)&hi << 16) | (unsigned)*(unsigned short*)&lo;
        }
        if constexpr (VEC == 8) *(uint4*)p = *(uint4*)&w[0];
        else                    *(uint2*)p = *(uint2*)&w[0];
    }
}

// ---------------------------------------------------------------- dtype detect
__global__ void detect_dtype_kernel(const unsigned short* __restrict__ x, int* __restrict__ flag) {
    __shared__ float s[256];
    float m = 0.0f;
    for (int i = threadIdx.x; i < 512; i += 256) {
        unsigned int u = ((unsigned int)x[i]) << 16;
        float v = __uint_as_float(u);
        if (!isnan(v)) m = fmaxf(m, fabsf(v));
    }
    s[threadIdx.x] = m;
    __syncthreads();
    for (int o = 128; o > 0; o >>= 1) {
        if (threadIdx.x < (unsigned)o) s[threadIdx.x] = fmaxf(s[threadIdx.x], s[threadIdx.x + o]);
        __syncthreads();
    }
    if (threadIdx.x == 0) flag[0] = (s[0] > 1e3f) ? 0 : 1;
}

// ---------------------------------------------------------------- fused converts
struct CvtJobs {
    const void* src[14];
    float* dst[14];
    int off[15];
    int cnt;
};
__global__ void cvt_fused_kernel(CvtJobs j, const int* __restrict__ flag) {
    int t = blockIdx.x * 256 + threadIdx.x;
    if (t >= j.off[j.cnt]) return;
    int k = 0;
    while (t >= j.off[k + 1]) ++k;
    int e = t - j.off[k];
    float v = *flag ? (float)((const bf16*)j.src[k])[e] : ((const float*)j.src[k])[e];
    j.dst[k][e] = v;
}

// W[K][N] (raw dtype per flag) -> Wt[N][K] bf16, three jobs fused
struct WtJobs {
    const void* src[3];
    bf16* dst[3];
    int K[3], N[3];
    int off[4];
};
__global__ void wt_fused_kernel(WtJobs j, const int* __restrict__ flag) {
    int t = blockIdx.x * 256 + threadIdx.x;
    if (t >= j.off[3]) return;
    int k_ = 0;
    while (t >= j.off[k_ + 1]) ++k_;
    int e = t - j.off[k_];
    int K = j.K[k_], Nn = j.N[k_];
    int n = e / K, kk = e % K;
    size_t si = (size_t)kk * Nn + n;
    float v = *flag ? (float)((const bf16*)j.src[k_])[si] : ((const float*)j.src[k_])[si];
    j.dst[k_][e] = (bf16)v;
}

__global__ void out_kernel(const float* __restrict__ in, void* __restrict__ out,
                           int n, const int* __restrict__ flag) {
    int i = blockIdx.x * blockDim.x + threadIdx.x;
    if (i >= n) return;
    if (*flag) ((bf16*)out)[i] = (bf16)in[i];
    else       ((float*)out)[i] = in[i];
}

// ---------------------------------------------------------------- CSR build
__global__ void zero_int_kernel(int* a, int n) {
    int i = blockIdx.x * blockDim.x + threadIdx.x;
    if (i < n) a[i] = 0;
}

__global__ void hist_kernel(const int* __restrict__ col, int* __restrict__ counts, int E) {
    int e = blockIdx.x * blockDim.x + threadIdx.x;
    if (e < E) atomicAdd(&counts[col[e]], 1);
}

// exclusive scan of counts -> offsets; also dis[i]=rsqrt(count+1) and counts[i]=0
__global__ void scan_dis_kernel(int* __restrict__ counts, int* __restrict__ offsets,
                                float* __restrict__ dis, int n) {
    __shared__ int sdata[1024];
    int carry = 0;
    if (threadIdx.x == 0) offsets[0] = 0;
    for (int base = 0; base < n; base += 1024) {
        int i = base + (int)threadIdx.x;
        int v = (i < n) ? counts[i] : 0;
        if (i < n) { dis[i] = rsqrtf((float)(v + 1)); counts[i] = 0; }
        sdata[threadIdx.x] = v;
        __syncthreads();
        for (int off = 1; off < 1024; off <<= 1) {
            int t = (threadIdx.x >= (unsigned)off) ? sdata[threadIdx.x - off] : 0;
            __syncthreads();
            sdata[threadIdx.x] += t;
            __syncthreads();
        }
        int inc = sdata[threadIdx.x] + carry;
        if (i < n) offsets[i + 1] = inc;
        carry += sdata[1023];
        __syncthreads();
    }
}

__global__ void fill_kernel(const int* __restrict__ row, const int* __restrict__ col,
                            const int* __restrict__ offsets, int* __restrict__ cursor,
                            int* __restrict__ csr_src, int E) {
    int e = blockIdx.x * blockDim.x + threadIdx.x;
    if (e < E) {
        int d = col[e];
        int pos = offsets[d] + atomicAdd(&cursor[d], 1);
        csr_src[pos] = row[e];
    }
}

// ---------------------------------------------------------------- aggregation
// scalar version (tiny F only)
template <typename TIn, typename TOut>
__global__ void agg_kernel(const TIn* __restrict__ h, const int* __restrict__ offsets,
                           const int* __restrict__ csr_src, const float* __restrict__ dis,
                           const float* __restrict__ bias, TOut* __restrict__ out,
                           int n, int F, int add_bias, int relu) {
    long long idx = (long long)blockIdx.x * blockDim.x + threadIdx.x;
    long long total = (long long)n * F;
    if (idx >= total) return;
    int i = (int)(idx / F);
    int f = (int)(idx % F);
    float di = dis[i];
    float acc = di * ldf(h, (size_t)i * F + f);
    int e0 = offsets[i], e1 = offsets[i + 1];
    for (int e = e0; e < e1; ++e) {
        int s = csr_src[e];
        acc += dis[s] * ldf(h, (size_t)s * F + f);
    }
    acc *= di;
    if (add_bias) acc += bias[f];
    if (relu) acc = fmaxf(acc, 0.0f);
    stf(out, (size_t)idx, acc);
}

// vectorized: thread owns VEC consecutive features (16B loads)
template <int F, int DO_BIAS, int DO_RELU, typename TIn, typename TOut>
__global__ __launch_bounds__(256) void agg_vec_kernel(
        const TIn* __restrict__ h, const int* __restrict__ offsets,
        const int* __restrict__ csr_src, const float* __restrict__ dis,
        const float* __restrict__ bias, TOut* __restrict__ out, int n) {
    constexpr int VEC = 16 / sizeof(TIn);
    constexpr int CPL = F / VEC;
    int t = blockIdx.x * 256 + threadIdx.x;
    if (t >= n * CPL) return;
    int i = t / CPL;
    int c = t % CPL;
    int fbase = c * VEC;
    float di = dis[i];
    float acc[VEC];
    loadvec(h + (size_t)i * F + fbase, acc);
    #pragma unroll
    for (int v = 0; v < VEC; ++v) acc[v] *= di;
    int e0 = offsets[i], e1 = offsets[i + 1];
    for (int e = e0; e < e1; ++e) {
        int s = csr_src[e];
        float dsv = dis[s];
        float tmp[VEC];
        loadvec(h + (size_t)s * F + fbase, tmp);
        #pragma unroll
        for (int v = 0; v < VEC; ++v) acc[v] += dsv * tmp[v];
    }
    #pragma unroll
    for (int v = 0; v < VEC; ++v) {
        acc[v] *= di;
        if (DO_BIAS) acc[v] += bias[fbase + v];
        if (DO_RELU) acc[v] = fmaxf(acc[v], 0.0f);
    }
    storevec<VEC>(out + (size_t)i * F + fbase, acc);
}

// ---------------------------------------------------------------- GEMMs
template <typename TIn, typename TOut>
__global__ void gemm_naive_kernel(const TIn* __restrict__ A, const float* __restrict__ W,
                                  const float* __restrict__ bias, TOut* __restrict__ C,
                                  int M, int Nc, int K, int add_bias, int relu) {
    long long idx = (long long)blockIdx.x * blockDim.x + threadIdx.x;
    long long total = (long long)M * Nc;
    if (idx >= total) return;
    int m = (int)(idx / Nc);
    int nc = (int)(idx % Nc);
    float acc = 0.0f;
    for (int k = 0; k < K; ++k)
        acc += ldf(A, (size_t)m * K + k) * W[(size_t)k * Nc + nc];
    if (add_bias) acc += bias[nc];
    if (relu) acc = fmaxf(acc, 0.0f);
    stf(C, (size_t)idx, acc);
}

// fp32 tiled GEMM (L1-L3): 64x64 tile, K%16==0, Nc%64==0.
#define TM 64
#define TN 64
#define TK 16
template <typename TIn, typename TOut>
__global__ __launch_bounds__(256) void gemm_tiled_kernel(
        const TIn* __restrict__ A, const float* __restrict__ W,
        const float* __restrict__ bias, TOut* __restrict__ C,
        int M, int Nc, int K, int add_bias, int relu) {
    __shared__ float As[TK][TM + 1];
    __shared__ float Bs[TK][TN + 1];
    int bm = blockIdx.x * TM;
    int bn = blockIdx.y * TN;
    int tid = threadIdx.x;
    int tm = (tid >> 4) << 2;
    int tn = (tid & 15) << 2;
    float acc[4][4] = {};
    for (int k0 = 0; k0 < K; k0 += TK) {
        #pragma unroll
        for (int l = 0; l < 4; ++l) {
            int idx = tid + l * 256;
            int m = idx >> 4;
            int k = idx & 15;
            int gm = bm + m;
            As[k][m] = (gm < M) ? ldf(A, (size_t)gm * K + k0 + k) : 0.0f;
        }
        #pragma unroll
        for (int l = 0; l < 4; ++l) {
            int idx = tid + l * 256;
            int k = idx >> 6;
            int nn = idx & 63;
            Bs[k][nn] = W[(size_t)(k0 + k) * Nc + bn + nn];
        }
        __syncthreads();
        #pragma unroll
        for (int k = 0; k < TK; ++k) {
            float a[4], b[4];
            #pragma unroll
            for (int i = 0; i < 4; ++i) a[i] = As[k][tm + i];
            #pragma unroll
            for (int j = 0; j < 4; ++j) b[j] = Bs[k][tn + j];
            #pragma unroll
            for (int i = 0; i < 4; ++i)
                #pragma unroll
                for (int j = 0; j < 4; ++j) acc[i][j] += a[i] * b[j];
        }
        __syncthreads();
    }
    #pragma unroll
    for (int i = 0; i < 4; ++i) {
        int gm = bm + tm + i;
        if (gm >= M) continue;
        #pragma unroll
        for (int j = 0; j < 4; ++j) {
            int gn = bn + tn + j;
            float v = acc[i][j];
            if (add_bias) v += bias[gn];
            if (relu) v = fmaxf(v, 0.0f);
            stf(C, (size_t)gm * Nc + gn, v);
        }
    }
}

// ---------------------------------------------------------------- MFMA GEMM
// C[M,Nc] = A[M,K](bf16) @ Bt[Nc,K](bf16)^T, fp32 accum. 128x128 tile, BK=32.
// Staging via global_load_lds width=16: LDS dest = wave-uniform base + lane*16,
// which our e=(pass*256+tid)*8 element layout satisfies exactly.
template <int DO_BIAS, int DO_RELU, typename TOut>
__global__ __launch_bounds__(256) void gemm_mfma_kernel(
        const bf16* __restrict__ A,   // [M,K]
        const bf16* __restrict__ Bt,  // [Nc,K]
        const float* __restrict__ bias,
        TOut* __restrict__ C,         // [M,Nc]
        int M, int Nc, int K) {
    __shared__ bf16 As[128 * 32];
    __shared__ bf16 Bs[128 * 32];
    const int tid  = threadIdx.x;
    const int wave = tid >> 6;
    const int lane = tid & 63;
    const int bm = blockIdx.x * 128;
    const int bn = blockIdx.y * 128;
    const int wr = (wave >> 1) * 64;
    const int wc = (wave & 1) * 64;
    const int fm = lane & 15;
    const int fq = lane >> 4;
    const int fk = fq * 8;

    // per-thread staging coords (two 16B chunks per 128x32 tile)
    const int e0 = tid * 8;
    const int r0 = e0 >> 5, c0 = e0 & 31;
    const int e1 = (256 + tid) * 8;
    const int r1 = e1 >> 5, c1 = e1 & 31;
    int gmA0 = bm + r0; if (gmA0 > M - 1) gmA0 = M - 1;
    int gmA1 = bm + r1; if (gmA1 > M - 1) gmA1 = M - 1;

    floatx4 acc[4][4] = {};

    for (int k0 = 0; k0 < K; k0 += 32) {
        __syncthreads();
        async16(A  + (size_t)gmA0     * K + k0 + c0, &As[e0]);
        async16(A  + (size_t)gmA1     * K + k0 + c1, &As[e1]);
        async16(Bt + (size_t)(bn + r0) * K + k0 + c0, &Bs[e0]);
        async16(Bt + (size_t)(bn + r1) * K + k0 + c1, &Bs[e1]);
        __syncthreads();
        short8 af[4], bfv[4];
        #pragma unroll
        for (int t = 0; t < 4; ++t) {
            af[t]  = *(const short8*)(&As[(wr + t * 16 + fm) * 32 + fk]);
            bfv[t] = *(const short8*)(&Bs[(wc + t * 16 + fm) * 32 + fk]);
        }
        #pragma unroll
        for (int mt = 0; mt < 4; ++mt)
            #pragma unroll
            for (int nt = 0; nt < 4; ++nt)
                acc[mt][nt] = __builtin_amdgcn_mfma_f32_16x16x32_bf16(
                    af[mt], bfv[nt], acc[mt][nt], 0, 0, 0);
    }

    #pragma unroll
    for (int mt = 0; mt < 4; ++mt) {
        #pragma unroll
        for (int r = 0; r < 4; ++r) {
            int gm = bm + wr + mt * 16 + fq * 4 + r;
            if (gm >= M) continue;
            #pragma unroll
            for (int nt = 0; nt < 4; ++nt) {
                int gn = bn + wc + nt * 16 + fm;
                float v = acc[mt][nt][r];
                if (DO_BIAS) v += bias[gn];
                if (DO_RELU) v = fmaxf(v, 0.0f);
                stf(C, (size_t)gm * Nc + gn, v);
            }
        }
    }
}

// ---------------------------------------------------------------- driver

static inline int cdiv(long long a, int b) { return (int)((a + b - 1) / b); }

extern "C" void kernel_launch(void* const* d_in, const int* in_sizes, int n_in,
                              void* d_out, int out_size, void* d_ws, size_t ws_size,
                              hipStream_t stream) {
    const int N = in_sizes[0] / 3;
    const int E = in_sizes[1] / 2;

    const int* edge_index = (const int*)d_in[1];
    const int* row = edge_index;       // sources
    const int* col = edge_index + E;   // destinations

    char* p = (char*)d_ws;
    auto alloc = [&](size_t bytes) {
        void* r = (void*)p;
        p += (bytes + 255) & ~(size_t)255;
        return r;
    };
    void* bufA    = alloc((size_t)N * 2048);   // max(N*1024 bf16, N*512 f32)
    void* bufB    = alloc((size_t)N * 1024);   // max(N*512 bf16, N*256 f32)
    float* dis    = (float*)alloc((size_t)N * sizeof(float));
    int* offsets  = (int*)alloc((size_t)(N + 1) * sizeof(int));
    int* cursor   = (int*)alloc((size_t)N * sizeof(int));
    int* csr_src  = (int*)alloc((size_t)E * sizeof(int));
    int* flag     = (int*)alloc(256);
    // fp32 weights needed only for non-MFMA layers; biases all layers
    const int WfL[5] = {0, 1, 2, 3, 7};
    float* Wf[8] = {};
    float* bf_[8];
    for (int t = 0; t < 5; ++t) {
        int L = WfL[t];
        Wf[L] = (float*)alloc((size_t)in_sizes[2 + 2 * L] * sizeof(float));
    }
    for (int L = 0; L < 8; ++L)
        bf_[L] = (float*)alloc((size_t)in_sizes[3 + 2 * L] * sizeof(float));
    bf16* Wt4 = (bf16*)alloc((size_t)128 * 1024 * sizeof(bf16));
    bf16* Wt5 = (bf16*)alloc((size_t)1024 * 512 * sizeof(bf16));
    bf16* Wt6 = (bf16*)alloc((size_t)512 * 256 * sizeof(bf16));
    size_t needed = (size_t)(p - (char*)d_ws);
    if (ws_size < needed) return;

    float* fA = (float*)bufA;  bf16* hA = (bf16*)bufA;
    float* fB = (float*)bufB;  bf16* hB = (bf16*)bufB;

    const int T = 256;

    // ---- dtype detect ----
    detect_dtype_kernel<<<1, 256, 0, stream>>>((const unsigned short*)d_in[0], flag);

    // ---- fused fp32 converts: x, W{0,1,2,3,7}, b0..b7 (14 jobs) ----
    {
        CvtJobs cj{};
        int idx = 0, cum = 0;
        auto add = [&](const void* s, float* d, int n) {
            cj.src[idx] = s; cj.dst[idx] = d; cj.off[idx] = cum; cum += n; ++idx;
        };
        add(d_in[0], fA, N * 3);
        for (int t = 0; t < 5; ++t) {
            int L = WfL[t];
            add(d_in[2 + 2 * L], Wf[L], in_sizes[2 + 2 * L]);
        }
        for (int L = 0; L < 8; ++L)
            add(d_in[3 + 2 * L], bf_[L], in_sizes[3 + 2 * L]);
        cj.off[idx] = cum; cj.cnt = idx;
        cvt_fused_kernel<<<cdiv(cum, T), T, 0, stream>>>(cj, flag);
    }

    // ---- fused bf16 weight transposes (reads raw inputs per flag) ----
    {
        WtJobs wj{};
        wj.src[0] = d_in[2 + 2 * 4]; wj.dst[0] = Wt4; wj.K[0] = 128;  wj.N[0] = 1024;
        wj.src[1] = d_in[2 + 2 * 5]; wj.dst[1] = Wt5; wj.K[1] = 1024; wj.N[1] = 512;
        wj.src[2] = d_in[2 + 2 * 6]; wj.dst[2] = Wt6; wj.K[2] = 512;  wj.N[2] = 256;
        wj.off[0] = 0;
        wj.off[1] = 128 * 1024;
        wj.off[2] = 128 * 1024 + 1024 * 512;
        wj.off[3] = 128 * 1024 + 1024 * 512 + 512 * 256;
        wt_fused_kernel<<<cdiv(wj.off[3], T), T, 0, stream>>>(wj, flag);
    }

    // ---- CSR build ----
    zero_int_kernel<<<cdiv(N, T), T, 0, stream>>>(cursor, N);
    hist_kernel<<<cdiv(E, T), T, 0, stream>>>(col, cursor, E);
    scan_dis_kernel<<<1, 1024, 0, stream>>>(cursor, offsets, dis, N);  // also re-zeroes cursor
    fill_kernel<<<cdiv(E, T), T, 0, stream>>>(row, col, offsets, cursor, csr_src, E);

    // Layer schedule (dims 3,64,64,64,128,1024,512,256,2). aggFirst when fin<fout.

    // L0: 3->64 aggFirst: scalar agg (F=3) -> fB, naive gemm (+b,relu) -> fA
    agg_kernel<float, float><<<cdiv((long long)N * 3, T), T, 0, stream>>>(
        fA, offsets, csr_src, dis, nullptr, fB, N, 3, 0, 0);
    gemm_naive_kernel<float, float><<<cdiv((long long)N * 64, T), T, 0, stream>>>(
        fB, Wf[0], bf_[0], fA, N, 64, 3, 1, 1);

    // L1: 64->64 gemmFirst: tiled f32 -> fB, agg_vec (+b,relu) -> fA
    {
        dim3 g(cdiv(N, TM), 64 / TN);
        gemm_tiled_kernel<float, float><<<g, 256, 0, stream>>>(fA, Wf[1], nullptr, fB, N, 64, 64, 0, 0);
        agg_vec_kernel<64, 1, 1, float, float><<<cdiv((long long)N * 16, T), T, 0, stream>>>(
            fB, offsets, csr_src, dis, bf_[1], fA, N);
    }

    // L2: 64->64 same
    {
        dim3 g(cdiv(N, TM), 64 / TN);
        gemm_tiled_kernel<float, float><<<g, 256, 0, stream>>>(fA, Wf[2], nullptr, fB, N, 64, 64, 0, 0);
        agg_vec_kernel<64, 1, 1, float, float><<<cdiv((long long)N * 16, T), T, 0, stream>>>(
            fB, offsets, csr_src, dis, bf_[2], fA, N);
    }

    // L3: 64->128 aggFirst: agg_vec f32 (F=64) -> fB, tiled (+b,relu) -> hA [N,128] bf16
    {
        agg_vec_kernel<64, 0, 0, float, float><<<cdiv((long long)N * 16, T), T, 0, stream>>>(
            fA, offsets, csr_src, dis, nullptr, fB, N);
        dim3 g(cdiv(N, TM), 128 / TN);
        gemm_tiled_kernel<float, bf16><<<g, 256, 0, stream>>>(fB, Wf[3], bf_[3], hA, N, 128, 64, 1, 1);
    }

    // L4: 128->1024 aggFirst: agg_vec bf16 (F=128) -> hB, MFMA (+b,relu) -> hA [N,1024] bf16
    {
        agg_vec_kernel<128, 0, 0, bf16, bf16><<<cdiv((long long)N * 16, T), T, 0, stream>>>(
            hA, offsets, csr_src, dis, nullptr, hB, N);
        dim3 g(cdiv(N, 128), 1024 / 128);
        gemm_mfma_kernel<1, 1, bf16><<<g, 256, 0, stream>>>(hB, Wt4, bf_[4], hA, N, 1024, 128);
    }

    // L5: 1024->512 gemmFirst: MFMA -> hB [N,512] bf16, agg_vec (+b,relu) -> hA bf16
    {
        dim3 g(cdiv(N, 128), 512 / 128);
        gemm_mfma_kernel<0, 0, bf16><<<g, 256, 0, stream>>>(hA, Wt5, nullptr, hB, N, 512, 1024);
        agg_vec_kernel<512, 1, 1, bf16, bf16><<<cdiv((long long)N * 64, T), T, 0, stream>>>(
            hB, offsets, csr_src, dis, bf_[5], hA, N);
    }

    // L6: 512->256 gemmFirst: MFMA -> hB [N,256] bf16, agg_vec (+b,relu) -> hA bf16
    {
        dim3 g(cdiv(N, 128), 256 / 128);
        gemm_mfma_kernel<0, 0, bf16><<<g, 256, 0, stream>>>(hA, Wt6, nullptr, hB, N, 256, 512);
        agg_vec_kernel<256, 1, 1, bf16, bf16><<<cdiv((long long)N * 32, T), T, 0, stream>>>(
            hB, offsets, csr_src, dis, bf_[6], hA, N);
    }

    // L7: 256->2 gemmFirst: naive bf16->f32 -> fB [N,2], scalar agg (+b, no relu) -> fA
    {
        gemm_naive_kernel<bf16, float><<<cdiv((long long)N * 2, T), T, 0, stream>>>(
            hA, Wf[7], nullptr, fB, N, 2, 256, 0, 0);
        agg_kernel<float, float><<<cdiv((long long)N * 2, T), T, 0, stream>>>(
            fB, offsets, csr_src, dis, bf_[7], fA, N, 2, 1, 0);
    }

    out_kernel<<<cdiv((long long)N * 2, T), T, 0, stream>>>(fA, d_out, N * 2, flag);
}